// Round 5
// baseline (118.466 us; speedup 1.0000x reference)
//
#include <hip/hip_runtime.h>

#define NN 512          // nodes
#define IND 512         // in features
#define NH 8            // heads
#define NF 64           // hidden per head

// ---------------------------------------------------------------------------
// K0: 512x512 fp32 transpose (z=0: X -> Xt, z=1: W_target -> Wtg_t)
// ---------------------------------------------------------------------------
__global__ __launch_bounds__(256) void transpose512(
    const float* __restrict__ X, float* __restrict__ Xt,
    const float* __restrict__ Wtg, float* __restrict__ Wtg_t)
{
    const float* src = blockIdx.z ? Wtg : X;
    float* dst       = blockIdx.z ? Wtg_t : Xt;
    __shared__ float tile[32][33];
    const int tid = threadIdx.x;
    const int tx = tid & 31, ty4 = (tid >> 5) * 4;
    const int x  = blockIdx.x * 32 + tx;
    const int y0 = blockIdx.y * 32 + ty4;
    #pragma unroll
    for (int r = 0; r < 4; ++r)
        tile[ty4 + r][tx] = src[(size_t)(y0 + r) * NN + x];
    __syncthreads();
    const int xo  = blockIdx.y * 32 + tx;
    const int yo0 = blockIdx.x * 32 + ty4;
    #pragma unroll
    for (int r = 0; r < 4; ++r)
        dst[(size_t)(yo0 + r) * NN + xo] = tile[tx][ty4 + r];
}

// ---------------------------------------------------------------------------
// K1: TN GEMM, no LDS staging: C[r][c] = sum_k S[r][k] * V[k][c]
//   S row-operand: wave-uniform address -> s_load through K$
//   V col-operand: lane on c -> coalesced global_load_dword
// z=0: Gs_t[o][n] = sum_k Ws[o][k] * Xt[k][n]
// z=1: Gt  [n][o] = sum_k X [n][k] * Wtg_t[k][o]
// 1024 blocks (8 rows x 64 cols each, 4-way wave split-K, LDS reduce)
// -> 4 blocks/CU, 4 waves/SIMD.
// ---------------------------------------------------------------------------
__global__ __launch_bounds__(256) void gemm_tn(
    const float* __restrict__ Ws, const float* __restrict__ Xt, float* __restrict__ Gs_t,
    const float* __restrict__ X,  const float* __restrict__ Wtg_t, float* __restrict__ Gt)
{
    const int mat = blockIdx.z;
    const float* S = mat ? X : Ws;
    const float* V = mat ? Wtg_t : Xt;
    float*       C = mat ? Gt : Gs_t;

    __shared__ float sp[4][8][64];

    const int tid  = threadIdx.x;
    const int kh   = __builtin_amdgcn_readfirstlane(tid >> 6);
    const int lane = tid & 63;
    const int r0 = blockIdx.y * 8;
    const int c0 = blockIdx.x * 64;

    const float* Sp = S + (size_t)r0 * IND + kh * 128;
    const float* Vp = V + (size_t)(kh * 128) * NN + c0 + lane;

    float acc[8] = {0.f, 0.f, 0.f, 0.f, 0.f, 0.f, 0.f, 0.f};
    #pragma unroll 4
    for (int k = 0; k < 128; ++k) {
        float v = Vp[(size_t)k * NN];
        #pragma unroll
        for (int r = 0; r < 8; ++r)
            acc[r] = fmaf(Sp[(size_t)r * IND + k], v, acc[r]);
    }
    #pragma unroll
    for (int r = 0; r < 8; ++r) sp[kh][r][lane] = acc[r];
    __syncthreads();
    #pragma unroll
    for (int q = 0; q < 2; ++q) {
        const int o = tid + q * 256;
        const int r = o >> 6, c = o & 63;
        C[(size_t)(r0 + r) * NN + c0 + c] =
            sp[0][r][c] + sp[1][r][c] + sp[2][r][c] + sp[3][r][c];
    }
}

// ---------------------------------------------------------------------------
// K2: per (i-tile of 4, head h) block.
//   phase 1: scores from Gs_t (coalesced over j) + uniform s_loads of Gt/w;
//            w*lrelu(t) = 0.6w*t + 0.4w*|t|
//   phase 2: softmax over j (no max pass: |score| <= ~45, fp32-exp safe);
//            write att_t[i][h][j] to ws -- coalesced.
//   phase 3: head_output = att @ Gt.
// ---------------------------------------------------------------------------
__global__ __launch_bounds__(256) void gat_attn(
    const float* __restrict__ Gs_t,      // [512 (h*64+f)][512 j]
    const float* __restrict__ Gt,        // [512 n][512 (h*64+f)]
    const float* __restrict__ attn_w,    // [64]
    const int*   __restrict__ adj,       // [512][512]
    float* __restrict__ out_feat,        // [512][512]
    float* __restrict__ att_t)           // ws: [512 i][8 h][512 j]
{
    __shared__ float s_sc[4][512];
    __shared__ float s_red[4][4][64];

    const int tid = threadIdx.x;
    const int i0  = blockIdx.x * 4;
    const int h   = blockIdx.y;

    // ---- phase 1: scores (2 j's per thread) ----
    {
        const int jj = tid * 2;
        float2 a0 = {0.f,0.f}, a1 = {0.f,0.f}, a2 = {0.f,0.f}, a3 = {0.f,0.f};
        const float* gsp = Gs_t + (size_t)h * NF * NN + jj;
        const float* gtp = Gt + (size_t)i0 * IND + h * NF;
        #pragma unroll 4
        for (int f = 0; f < NF; ++f) {
            float w  = attn_w[f];            // uniform -> s_load
            float w6 = 0.6f * w, w4 = 0.4f * w;
            float2 g = *reinterpret_cast<const float2*>(gsp + (size_t)f * NN);
            float gt0 = gtp[f];              // uniform -> s_load
            float gt1 = gtp[IND + f];
            float gt2 = gtp[2 * IND + f];
            float gt3 = gtp[3 * IND + f];
            float tx, ty;
            tx = g.x + gt0; ty = g.y + gt0;
            a0.x = fmaf(w4, fabsf(tx), fmaf(w6, tx, a0.x));
            a0.y = fmaf(w4, fabsf(ty), fmaf(w6, ty, a0.y));
            tx = g.x + gt1; ty = g.y + gt1;
            a1.x = fmaf(w4, fabsf(tx), fmaf(w6, tx, a1.x));
            a1.y = fmaf(w4, fabsf(ty), fmaf(w6, ty, a1.y));
            tx = g.x + gt2; ty = g.y + gt2;
            a2.x = fmaf(w4, fabsf(tx), fmaf(w6, tx, a2.x));
            a2.y = fmaf(w4, fabsf(ty), fmaf(w6, ty, a2.y));
            tx = g.x + gt3; ty = g.y + gt3;
            a3.x = fmaf(w4, fabsf(tx), fmaf(w6, tx, a3.x));
            a3.y = fmaf(w4, fabsf(ty), fmaf(w6, ty, a3.y));
        }
        int2 ad;
        ad = *reinterpret_cast<const int2*>(adj + (size_t)(i0 + 0) * NN + jj);
        s_sc[0][jj]     = ad.x ? a0.x : -INFINITY;
        s_sc[0][jj + 1] = ad.y ? a0.y : -INFINITY;
        ad = *reinterpret_cast<const int2*>(adj + (size_t)(i0 + 1) * NN + jj);
        s_sc[1][jj]     = ad.x ? a1.x : -INFINITY;
        s_sc[1][jj + 1] = ad.y ? a1.y : -INFINITY;
        ad = *reinterpret_cast<const int2*>(adj + (size_t)(i0 + 2) * NN + jj);
        s_sc[2][jj]     = ad.x ? a2.x : -INFINITY;
        s_sc[2][jj + 1] = ad.y ? a2.y : -INFINITY;
        ad = *reinterpret_cast<const int2*>(adj + (size_t)(i0 + 3) * NN + jj);
        s_sc[3][jj]     = ad.x ? a3.x : -INFINITY;
        s_sc[3][jj + 1] = ad.y ? a3.y : -INFINITY;
    }
    __syncthreads();

    // ---- phase 2: softmax over j; coalesced att_t write ----
    {
        const int ii = tid >> 6, lane = tid & 63;
        float e[8];
        float sum = 0.f;
        #pragma unroll
        for (int r = 0; r < 8; ++r) {
            float ev = __expf(s_sc[ii][lane + r * 64]);
            e[r] = ev;
            sum += ev;
        }
        #pragma unroll
        for (int off = 32; off >= 1; off >>= 1) sum += __shfl_xor(sum, off, 64);
        float inv = 1.f / sum;
        float* arow = att_t + ((size_t)(i0 + ii) * NH + h) * NN;
        #pragma unroll
        for (int r = 0; r < 8; ++r) {
            const int j = lane + r * 64;
            float a = e[r] * inv;
            s_sc[ii][j] = a;
            arow[j] = a;
        }
    }
    __syncthreads();

    // ---- phase 3: head_output = att @ Gt (waves split j) ----
    {
        const int w = tid >> 6, lane = tid & 63;
        const int jb = w * 128;
        float o0 = 0.f, o1 = 0.f, o2 = 0.f, o3 = 0.f;
        const float* gtc = Gt + h * NF + lane;
        #pragma unroll 4
        for (int s = 0; s < 32; ++s) {
            const int j = jb + 4 * s;
            float4 b0 = *reinterpret_cast<const float4*>(&s_sc[0][j]);
            float4 b1 = *reinterpret_cast<const float4*>(&s_sc[1][j]);
            float4 b2 = *reinterpret_cast<const float4*>(&s_sc[2][j]);
            float4 b3 = *reinterpret_cast<const float4*>(&s_sc[3][j]);
            float gv;
            gv = gtc[(size_t)(j + 0) * IND];
            o0 = fmaf(b0.x, gv, o0); o1 = fmaf(b1.x, gv, o1);
            o2 = fmaf(b2.x, gv, o2); o3 = fmaf(b3.x, gv, o3);
            gv = gtc[(size_t)(j + 1) * IND];
            o0 = fmaf(b0.y, gv, o0); o1 = fmaf(b1.y, gv, o1);
            o2 = fmaf(b2.y, gv, o2); o3 = fmaf(b3.y, gv, o3);
            gv = gtc[(size_t)(j + 2) * IND];
            o0 = fmaf(b0.z, gv, o0); o1 = fmaf(b1.z, gv, o1);
            o2 = fmaf(b2.z, gv, o2); o3 = fmaf(b3.z, gv, o3);
            gv = gtc[(size_t)(j + 3) * IND];
            o0 = fmaf(b0.w, gv, o0); o1 = fmaf(b1.w, gv, o1);
            o2 = fmaf(b2.w, gv, o2); o3 = fmaf(b3.w, gv, o3);
        }
        s_red[w][0][lane] = o0; s_red[w][1][lane] = o1;
        s_red[w][2][lane] = o2; s_red[w][3][lane] = o3;
    }
    __syncthreads();
    {
        const int ii = tid >> 6, f = tid & 63;
        float s = s_red[0][ii][f] + s_red[1][ii][f] + s_red[2][ii][f] + s_red[3][ii][f];
        out_feat[(size_t)(i0 + ii) * (NH * NF) + h * NF + f] = s;
    }
}

// ---------------------------------------------------------------------------
// K3: att_t [i][h][j] -> out_att [i][j][h]; one block per i; LDS bounce,
// coalesced reads and float4 contiguous writes.
// ---------------------------------------------------------------------------
__global__ __launch_bounds__(256) void att_tr(
    const float* __restrict__ att_t, float* __restrict__ out_att)
{
    __shared__ float t[NH][NN];   // 16 KB
    const int tid = threadIdx.x;
    const int i = blockIdx.x;
    const float* in = att_t + (size_t)i * NH * NN;
    #pragma unroll
    for (int q = 0; q < 2; ++q) {
        const int j = tid + q * 256;
        #pragma unroll
        for (int h = 0; h < NH; ++h)
            t[h][j] = in[(size_t)h * NN + j];
    }
    __syncthreads();
    float* out = out_att + (size_t)i * NN * NH;
    const int j0 = tid * 2;
    #pragma unroll
    for (int jj = 0; jj < 2; ++jj) {
        const int j = j0 + jj;
        float4 a = { t[0][j], t[1][j], t[2][j], t[3][j] };
        float4 b = { t[4][j], t[5][j], t[6][j], t[7][j] };
        reinterpret_cast<float4*>(out + (size_t)j * NH)[0] = a;
        reinterpret_cast<float4*>(out + (size_t)j * NH)[1] = b;
    }
}

extern "C" void kernel_launch(void* const* d_in, const int* in_sizes, int n_in,
                              void* d_out, int out_size, void* d_ws, size_t ws_size,
                              hipStream_t stream) {
    const float* X   = (const float*)d_in[0];   // h [1,512,512]
    const float* Ws  = (const float*)d_in[1];   // W_source [512,512]
    const float* Wtg = (const float*)d_in[2];   // W_target [512,512]
    const float* aw  = (const float*)d_in[3];   // attn_w [64]
    const int*   adj = (const int*)d_in[4];     // adjacency [512,512,1]

    float* Xt    = (float*)d_ws;                  // [512 k][512 n]
    float* Wtg_t = Xt    + (size_t)NN * IND;      // [512 k][512 o]
    float* Gs_t  = Wtg_t + (size_t)NN * IND;      // [512 o][512 n]
    float* Gt    = Gs_t  + (size_t)NN * IND;      // [512 n][512 o]
    float* att_t = Gt    + (size_t)NN * IND;      // [512 i][8 h][512 j]

    float* out_feat = (float*)d_out;                    // [512,512]
    float* out_att  = out_feat + (size_t)NN * NH * NF;  // [512,512,8]

    hipLaunchKernelGGL(transpose512, dim3(16, 16, 2), dim3(256), 0, stream,
                       X, Xt, Wtg, Wtg_t);
    hipLaunchKernelGGL(gemm_tn, dim3(8, 64, 2), dim3(256), 0, stream,
                       Ws, Xt, Gs_t, X, Wtg_t, Gt);
    hipLaunchKernelGGL(gat_attn, dim3(NN / 4, NH), dim3(256), 0, stream,
                       Gs_t, Gt, aw, adj, out_feat, att_t);
    hipLaunchKernelGGL(att_tr, dim3(NN), dim3(256), 0, stream,
                       att_t, out_att);
}